// Round 1
// baseline (5014.591 us; speedup 1.0000x reference)
//
#include <hip/hip_runtime.h>
#include <stdint.h>

// CapsuleNet forward on MI355X.
// Pipeline: conv1(fp32 VALU) -> h bf16 -> conv2 as implicit-GEMM bf16 MFMA
// (M=256 co, N=18432 b*36+s, K=20736 t*256+ci) -> squash in place ->
// 3x dynamic routing (VALU kernels; W stays fp32).
// Workspace layout (needs ~134.8 MB):
//   h bf16 [512][256][20][20]            @0         104,857,600 B
//   A2 bf16 [256][20736] (k=t*256+ci)    @104857600  10,616,832 B
//   u  f32 [512][1152][8] (conv2 out)    @115474432  18,874,368 B
//   v  f32 [512][10][16]                 @134348800     327,680 B
//   bij f32 [1152][10]                   @134676480      46,080 B
//   cT  f32 [10][1152]                   @134722560      46,080 B

typedef unsigned short u16;
typedef unsigned int u32;
typedef short short8 __attribute__((ext_vector_type(8)));
typedef float f32x4 __attribute__((ext_vector_type(4)));

__device__ __forceinline__ u16 f2bf(float f) {
  u32 u = __float_as_uint(f);
  return (u16)((u + 0x7FFFu + ((u >> 16) & 1u)) >> 16);
}

// ------------------- conv1 + bias + ReLU -> bf16 h -------------------
__global__ __launch_bounds__(256) void conv1_kernel(
    const float* __restrict__ x, const float* __restrict__ w1,
    const float* __restrict__ b1, u16* __restrict__ h) {
  int b = blockIdx.x;
  int co0 = blockIdx.y * 128;
  __shared__ float xs[784];
  const float* xb = x + (size_t)b * 784;
  for (int i = threadIdx.x; i < 784; i += 256) xs[i] = xb[i];
  __syncthreads();
  int t = threadIdx.x;
  if (t >= 200) return;  // 200 threads: 20 oh rows x 10 ow-pairs
  int oh = t / 10, owp = (t % 10) * 2;
  u16* hb = h + (size_t)b * 102400;
  for (int cc = 0; cc < 128; ++cc) {
    int co = co0 + cc;
    const float* wc = w1 + co * 81;  // block-uniform -> scalar loads
    float acc0 = 0.f, acc1 = 0.f;
#pragma unroll
    for (int kh = 0; kh < 9; ++kh) {
      const float* xrow = &xs[(oh + kh) * 28 + owp];
      float xr[10];
#pragma unroll
      for (int j = 0; j < 10; ++j) xr[j] = xrow[j];
#pragma unroll
      for (int kw = 0; kw < 9; ++kw) {
        float wv = wc[kh * 9 + kw];
        acc0 = fmaf(wv, xr[kw], acc0);
        acc1 = fmaf(wv, xr[kw + 1], acc1);
      }
    }
    float bias = b1[co];
    acc0 = fmaxf(acc0 + bias, 0.f);
    acc1 = fmaxf(acc1 + bias, 0.f);
    int o = co * 400 + oh * 20 + owp;
    hb[o] = f2bf(acc0);
    hb[o + 1] = f2bf(acc1);
  }
}

// ------------------- conv2 weight pre-transform: [co][ci][t] -> bf16 [co][t*256+ci] -------------------
__global__ __launch_bounds__(256) void prep_w2_kernel(
    const float* __restrict__ w2, u16* __restrict__ A2) {
  int idx = blockIdx.x * 256 + threadIdx.x;  // 5,308,416 total
  int co = idx / 20736, k = idx - co * 20736;
  int t = k >> 8, ci = k & 255;
  A2[idx] = f2bf(w2[(size_t)(co * 256 + ci) * 81 + t]);
}

// ------------------- conv2 implicit GEMM, bf16 MFMA 16x16x32 -------------------
// Block: 128(co) x 128(n) tile, BK=32, 256 threads = 4 waves (2x2 of 64x64).
// K order: k = t*256 + ci, t = kh*9+kw. Grid: 288 = 2 mb * 144 nb.
__global__ __launch_bounds__(256) void conv2_kernel(
    const u16* __restrict__ h, const u16* __restrict__ A2,
    const float* __restrict__ b2, float* __restrict__ out2) {
  __shared__ u16 Al[128 * 32];
  __shared__ u16 Bl[128 * 32];
  int bx = blockIdx.x;
  int mb = bx & 1, nbk = bx >> 1;
  int m0 = mb * 128, n0 = nbk * 128;
  int tid = threadIdx.x;
  int lane = tid & 63, wave = tid >> 6;
  int wr = wave >> 1, wc = wave & 1;

  // B-gather column owned by this thread (2 threads per column)
  int col = tid >> 1, half = tid & 1;
  int n = n0 + col;
  int nb_ = n / 36;
  int sp = n - nb_ * 36;
  int oh = sp / 6, ow = sp - oh * 6;
  const size_t bbase = (size_t)nb_ * 102400;

  int arow = tid >> 2, aq = tid & 3;

  f32x4 acc[4][4] = {};

  for (int t = 0; t < 81; ++t) {
    int kh = t / 9, kw = t - kh * 9;
    const u16* hcol = h + bbase + (2 * oh + kh) * 20 + (2 * ow + kw);
    for (int kk = 0; kk < 8; ++kk) {
      int ci0 = kk * 32;
      // A tile: 128 rows x 32 k (two 16B chunks per thread), issued early
      const u16* ap = A2 + (size_t)(m0 + arow) * 20736 + t * 256 + ci0 + aq * 8;
      uint4 av0 = *(const uint4*)ap;
      uint4 av1 = *(const uint4*)(ap + (size_t)64 * 20736);
      // B tile gather: 16 k-values down this column
      u32 bp[8];
      {
        const u16* p = hcol + (ci0 + half * 16) * 400;
#pragma unroll
        for (int j = 0; j < 8; ++j) {
          u32 lo = p[0], hi = p[400];
          bp[j] = lo | (hi << 16);
          p += 800;
        }
      }
      __syncthreads();  // prev MFMA reads done -> safe to overwrite LDS
      *(uint4*)&Al[arow * 32 + aq * 8] = av0;
      *(uint4*)&Al[(arow + 64) * 32 + aq * 8] = av1;
      *(uint4*)&Bl[col * 32 + half * 16] = *(uint4*)&bp[0];
      *(uint4*)&Bl[col * 32 + half * 16 + 8] = *(uint4*)&bp[4];
      __syncthreads();
      int fr = lane & 15, fk = (lane >> 4) * 8;
      short8 af[4], bf_[4];
#pragma unroll
      for (int m = 0; m < 4; ++m)
        af[m] = *(const short8*)&Al[(wr * 64 + m * 16 + fr) * 32 + fk];
#pragma unroll
      for (int nn = 0; nn < 4; ++nn)
        bf_[nn] = *(const short8*)&Bl[(wc * 64 + nn * 16 + fr) * 32 + fk];
#pragma unroll
      for (int m = 0; m < 4; ++m)
#pragma unroll
        for (int nn = 0; nn < 4; ++nn)
          acc[m][nn] = __builtin_amdgcn_mfma_f32_16x16x32_bf16(
              af[m], bf_[nn], acc[m][nn], 0, 0, 0);
    }
  }
  // epilogue: D col = lane&15 -> n; row = (lane>>4)*4+q -> co. out2[b][co*36+s]
  int fr = lane & 15, fq = lane >> 4;
#pragma unroll
  for (int nn = 0; nn < 4; ++nn) {
    int cn = n0 + wc * 64 + nn * 16 + fr;
    int ob = cn / 36;
    int os = cn - ob * 36;
    float* op = out2 + (size_t)ob * 9216 + os;
#pragma unroll
    for (int m = 0; m < 4; ++m) {
      int row0 = m0 + wr * 64 + m * 16 + fq * 4;
#pragma unroll
      for (int q = 0; q < 4; ++q) {
        int co = row0 + q;
        op[co * 36] = acc[m][nn][q] + b2[co];
      }
    }
  }
}

// ------------------- squash in place: u[b][r][8] -------------------
__global__ __launch_bounds__(256) void squash_kernel(float* __restrict__ u) {
  size_t idx = (size_t)blockIdx.x * 256 + threadIdx.x;  // 589824 capsules
  float4 a = *(float4*)(u + idx * 8);
  float4 b = *(float4*)(u + idx * 8 + 4);
  float sq = a.x * a.x + a.y * a.y + a.z * a.z + a.w * a.w +
             b.x * b.x + b.y * b.y + b.z * b.z + b.w * b.w;
  float f = sqrtf(sq) / (1.0f + sq);
  a.x *= f; a.y *= f; a.z *= f; a.w *= f;
  b.x *= f; b.y *= f; b.z *= f; b.w *= f;
  *(float4*)(u + idx * 8) = a;
  *(float4*)(u + idx * 8 + 4) = b;
}

// ------------------- softmax over routes: cT[c][r] = softmax_r(bij[r][c]) -------------------
__global__ __launch_bounds__(256) void softmax_c_kernel(
    const float* __restrict__ bij, float* __restrict__ cT) {
  int c = blockIdx.x;
  int tid = threadIdx.x;
  __shared__ float red[256];
  float mx = -1e30f;
  for (int r = tid; r < 1152; r += 256) mx = fmaxf(mx, bij[r * 10 + c]);
  red[tid] = mx;
  __syncthreads();
  for (int s = 128; s > 0; s >>= 1) {
    if (tid < s) red[tid] = fmaxf(red[tid], red[tid + s]);
    __syncthreads();
  }
  mx = red[0];
  __syncthreads();
  float sum = 0.f;
  for (int r = tid; r < 1152; r += 256) sum += expf(bij[r * 10 + c] - mx);
  red[tid] = sum;
  __syncthreads();
  for (int s = 128; s > 0; s >>= 1) {
    if (tid < s) red[tid] += red[tid + s];
    __syncthreads();
  }
  float inv = 1.0f / red[0];
  for (int r = tid; r < 1152; r += 256)
    cT[c * 1152 + r] = expf(bij[r * 10 + c] - mx) * inv;
}

// ------------------- s_j + squash -> v (or final output) -------------------
// grid (16,10): 32 batches x one capsule class. threads: lb=tid>>3 (b), g=tid&7 (o pair)
__global__ __launch_bounds__(256) void route_sv_kernel(
    const float* __restrict__ cT, const float* __restrict__ u,
    const float* __restrict__ W, float* __restrict__ vout) {
  int c = blockIdx.y, b0 = blockIdx.x * 32;
  int tid = threadIdx.x, lb = tid >> 3, g = tid & 7;
  __shared__ float us[32][32][8];
  __shared__ float cs[32];
  float acc0 = 0.f, acc1 = 0.f;
  for (int r0 = 0; r0 < 1152; r0 += 32) {
    __syncthreads();
    for (int i = tid; i < 2048; i += 256) {
      int bb = i >> 6, rr = (i >> 1) & 31, hf = i & 1;
      *(float4*)&us[bb][rr][hf * 4] =
          *(const float4*)&u[(((size_t)(b0 + bb)) * 1152 + r0 + rr) * 8 + hf * 4];
    }
    if (tid < 32) cs[tid] = cT[c * 1152 + r0 + tid];
    __syncthreads();
#pragma unroll 4
    for (int rr = 0; rr < 32; ++rr) {
      int r = r0 + rr;
      const float4* wp = (const float4*)&W[(((size_t)r * 10 + c) * 16 + 2 * g) * 8];
      float4 w0 = wp[0], w1 = wp[1], w2v = wp[2], w3 = wp[3];
      float4 ua = *(float4*)&us[lb][rr][0];
      float4 ub = *(float4*)&us[lb][rr][4];
      float d0 = w0.x * ua.x + w0.y * ua.y + w0.z * ua.z + w0.w * ua.w +
                 w1.x * ub.x + w1.y * ub.y + w1.z * ub.z + w1.w * ub.w;
      float d1 = w2v.x * ua.x + w2v.y * ua.y + w2v.z * ua.z + w2v.w * ua.w +
                 w3.x * ub.x + w3.y * ub.y + w3.z * ub.z + w3.w * ub.w;
      float cr = cs[rr];
      acc0 = fmaf(cr, d0, acc0);
      acc1 = fmaf(cr, d1, acc1);
    }
  }
  float sq = acc0 * acc0 + acc1 * acc1;
  sq += __shfl_xor(sq, 1, 64);
  sq += __shfl_xor(sq, 2, 64);
  sq += __shfl_xor(sq, 4, 64);
  float f = sqrtf(sq) / (1.0f + sq);
  float2 vv = make_float2(acc0 * f, acc1 * f);
  *(float2*)&vout[(((size_t)(b0 + lb)) * 10 + c) * 16 + 2 * g] = vv;
}

// ------------------- agreement: bij[r][c] += mean_b sum_o u_hat*v -------------------
// grid (16,10). threads: lb=tid>>3 (b), ii=tid&7 (input dim i)
__global__ __launch_bounds__(256) void route_agree_kernel(
    const float* __restrict__ u, const float* __restrict__ W,
    const float* __restrict__ v, float* __restrict__ bij) {
  int c = blockIdx.y, b0 = blockIdx.x * 32;
  int tid = threadIdx.x, lb = tid >> 3, ii = tid & 7;
  __shared__ float us[32][32][8];
  __shared__ float Wl[32][8][16];  // [rr][i][o]
  __shared__ float vl[32][16];
  __shared__ float ared[32];
  for (int i = tid; i < 32 * 16; i += 256) {
    int bb = i >> 4, o = i & 15;
    vl[bb][o] = v[((size_t)(b0 + bb) * 10 + c) * 16 + o];
  }
  __syncthreads();
  float vreg[16];
#pragma unroll
  for (int o = 0; o < 16; ++o) vreg[o] = vl[lb][o];

  for (int r0 = 0; r0 < 1152; r0 += 32) {
    __syncthreads();
    for (int i = tid; i < 2048; i += 256) {
      int bb = i >> 6, rr = (i >> 1) & 31, hf = i & 1;
      *(float4*)&us[bb][rr][hf * 4] =
          *(const float4*)&u[(((size_t)(b0 + bb)) * 1152 + r0 + rr) * 8 + hf * 4];
    }
    for (int i = tid; i < 1024; i += 256) {
      int rr = i >> 5, rem = i & 31;  // f4 rem covers (o=rem>>1, i=(rem&1)*4..+3)
      float4 wv = *(const float4*)&W[(((size_t)(r0 + rr) * 10 + c) * 16) * 8 + rem * 4];
      int o = rem >> 1, ib = (rem & 1) * 4;
      Wl[rr][ib + 0][o] = wv.x;
      Wl[rr][ib + 1][o] = wv.y;
      Wl[rr][ib + 2][o] = wv.z;
      Wl[rr][ib + 3][o] = wv.w;
    }
    if (tid < 32) ared[tid] = 0.f;
    __syncthreads();
    for (int rr = 0; rr < 32; ++rr) {
      float p = 0.f;
#pragma unroll
      for (int o = 0; o < 16; ++o) p = fmaf(Wl[rr][ii][o], vreg[o], p);
      float a = us[lb][rr][ii] * p;
      a += __shfl_xor(a, 1, 64);
      a += __shfl_xor(a, 2, 64);
      a += __shfl_xor(a, 4, 64);
      if (ii == 0) atomicAdd(&ared[rr], a);
    }
    __syncthreads();
    if (tid < 32)
      atomicAdd(&bij[(size_t)(r0 + tid) * 10 + c], ared[tid] * (1.0f / 512.0f));
  }
}

extern "C" void kernel_launch(void* const* d_in, const int* in_sizes, int n_in,
                              void* d_out, int out_size, void* d_ws, size_t ws_size,
                              hipStream_t stream) {
  const float* x  = (const float*)d_in[0];
  const float* w1 = (const float*)d_in[1];
  const float* b1 = (const float*)d_in[2];
  const float* w2 = (const float*)d_in[3];
  const float* b2 = (const float*)d_in[4];
  const float* W  = (const float*)d_in[5];
  char* ws = (char*)d_ws;
  u16*   h   = (u16*)ws;
  u16*   A2  = (u16*)(ws + 104857600);
  float* u   = (float*)(ws + 115474432);
  float* v   = (float*)(ws + 134348800);
  float* bij = (float*)(ws + 134676480);
  float* cT  = (float*)(ws + 134722560);
  float* out = (float*)d_out;

  hipMemsetAsync(bij, 0, 11520 * sizeof(float), stream);
  conv1_kernel<<<dim3(512, 2), 256, 0, stream>>>(x, w1, b1, h);
  prep_w2_kernel<<<20736, 256, 0, stream>>>(w2, A2);
  conv2_kernel<<<288, 256, 0, stream>>>(h, A2, b2, u);
  squash_kernel<<<2304, 256, 0, stream>>>(u);
  for (int it = 0; it < 3; ++it) {
    softmax_c_kernel<<<10, 256, 0, stream>>>(bij, cT);
    route_sv_kernel<<<dim3(16, 10), 256, 0, stream>>>(cT, u, W, (it == 2) ? out : v);
    if (it < 2) route_agree_kernel<<<dim3(16, 10), 256, 0, stream>>>(u, W, v, bij);
  }
}

// Round 2
// 831.235 us; speedup vs baseline: 6.0327x; 6.0327x over previous
//
#include <hip/hip_runtime.h>
#include <stdint.h>

// CapsuleNet forward on MI355X — round 2.
// conv1 (fp32 VALU, reg-patch) -> hT[b][y][x][ci] bf16 (channel-last)
// conv2 = implicit GEMM bf16 MFMA, global_load_lds w16, BK=64, XOR-swizzle,
//         split-K x4 with atomicAdd into bias-initialized u
// routing = GEMM-ified: s = ub @ (c*W)^T ; G = v^T u ; bij += W . G
//
// ws layout (total 134,768,640 B — same as proven round-1 footprint):
//   hT  bf16 [512][20][20][256]   @0           104,857,600
//   A2  bf16 [256][20736]         @104,857,600  10,616,832
//   u   f32  [512][9216]          @115,474,432  18,874,368
//   bij f32  [1152][10]           @134,348,800      46,080
//   cT  f32  [10][1152]           @134,394,880      46,080
//   s   f32  [160][512]           @134,440,960     327,680
//  aliased over dead hT after conv2:
//   ub  bf16 [512][9216]          @0             9,437,184
//   ubT bf16 [9216][512]          @9,437,184     9,437,184
//   Wcb bf16 [160][9216]          @18,874,368    2,949,120
//   vb  bf16 [160][512]           @21,823,488      163,840
//   G   f32  [160][9216]          @21,987,328    5,898,240

typedef unsigned short u16;
typedef unsigned int u32;
typedef short short8 __attribute__((ext_vector_type(8)));
typedef float f32x4 __attribute__((ext_vector_type(4)));

__device__ __forceinline__ u16 f2bf(float f) {
  u32 u = __float_as_uint(f);
  return (u16)((u + 0x7FFFu + ((u >> 16) & 1u)) >> 16);
}

__device__ __forceinline__ void gload_lds16(const void* g, void* l) {
  __builtin_amdgcn_global_load_lds(
      (const __attribute__((address_space(1))) void*)g,
      (__attribute__((address_space(3))) void*)l, 16, 0, 0);
}

// ---------------- conv1 + bias + ReLU -> hT[b][y][x][co] bf16 ----------------
// 200 active threads: (oh, ow-pair). 9x10 input patch held in registers;
// weights are block-uniform -> scalar loads. 2 outputs/thread share the patch.
__global__ __launch_bounds__(256) void conv1_kernel(
    const float* __restrict__ x, const float* __restrict__ w1,
    const float* __restrict__ b1, u16* __restrict__ hT) {
  int b = blockIdx.x;
  int co0 = blockIdx.y * 128;
  int t = threadIdx.x;
  if (t >= 200) return;
  int oh = t / 10, ow0 = (t % 10) * 2;
  const float* xb = x + (size_t)b * 784;
  float patch[9][10];
#pragma unroll
  for (int kh = 0; kh < 9; ++kh)
#pragma unroll
    for (int j = 0; j < 10; ++j) patch[kh][j] = xb[(oh + kh) * 28 + ow0 + j];
  u16* hb = hT + ((size_t)b * 400 + oh * 20 + ow0) * 256 + co0;
  for (int c8 = 0; c8 < 16; ++c8) {
    u16 o0[8], o1[8];
#pragma unroll
    for (int cc = 0; cc < 8; ++cc) {
      int co = co0 + c8 * 8 + cc;
      const float* wc = w1 + co * 81;  // block-uniform -> s_load
      float a0 = 0.f, a1 = 0.f;
#pragma unroll
      for (int kh = 0; kh < 9; ++kh)
#pragma unroll
        for (int kw = 0; kw < 9; ++kw) {
          float wv = wc[kh * 9 + kw];
          a0 = fmaf(wv, patch[kh][kw], a0);
          a1 = fmaf(wv, patch[kh][kw + 1], a1);
        }
      float bias = b1[co];
      o0[cc] = f2bf(fmaxf(a0 + bias, 0.f));
      o1[cc] = f2bf(fmaxf(a1 + bias, 0.f));
    }
    *(uint4*)(hb + c8 * 8) = *(uint4*)o0;
    *(uint4*)(hb + 256 + c8 * 8) = *(uint4*)o1;
  }
}

// ---------------- conv2 weights: [co][ci][t] -> bf16 [co][t*256+ci] ----------------
__global__ __launch_bounds__(256) void prep_w2_kernel(
    const float* __restrict__ w2, u16* __restrict__ A2) {
  int idx = blockIdx.x * 256 + threadIdx.x;  // 5,308,416
  int co = idx / 20736, k = idx - co * 20736;
  int t = k >> 8, ci = k & 255;
  A2[idx] = f2bf(w2[(size_t)(co * 256 + ci) * 81 + t]);
}

// ---------------- u := bias (pre-init for conv2 atomic accumulation) ----------------
__global__ __launch_bounds__(256) void init_u_kernel(
    const float* __restrict__ b2, float* __restrict__ u) {
  int i = blockIdx.x * 256 + threadIdx.x;  // 1,179,648 float4s
  int b = i / 2304, j0 = (i - b * 2304) * 4;
  float4 v;
  v.x = b2[j0 / 36]; v.y = b2[(j0 + 1) / 36];
  v.z = b2[(j0 + 2) / 36]; v.w = b2[(j0 + 3) / 36];
  *(float4*)(u + (size_t)b * 9216 + j0) = v;
}

// ---------------- conv2 implicit GEMM ----------------
// M=256(co) N=18432(b*36+s) K=81taps*256ci. Tile 128x128, BK=64, split-K x4.
// grid 1152 = 144 nb * 4 kz * 2 mb. global_load_lds w16, source-XOR-swizzle
// q^(row&7) (involution; linear LDS dest per rule #21) -> 2-way-free ds_read_b128.
__global__ __launch_bounds__(256) void conv2_kernel(
    const u16* __restrict__ hT, const u16* __restrict__ A2,
    float* __restrict__ u) {
  __shared__ __align__(16) u16 Al[128 * 64];
  __shared__ __align__(16) u16 Bl[128 * 64];
  int bx = blockIdx.x;
  int mb = bx & 1, kz = (bx >> 1) & 3, nbk = bx >> 3;
  int m0 = mb * 128, n0 = nbk * 128;
  int t_begin = (81 * kz) >> 2, t_end = (81 * (kz + 1)) >> 2;
  int tid = threadIdx.x;
  int lane = tid & 63, wave = tid >> 6;
  int wr = wave >> 1, wc = wave & 1;

  // staging: per wave 4 issues of 1KB each for A and B
  int srow8 = lane >> 3;         // 0..7
  int q = lane & 7;
  int rowbase = wave * 32 + srow8;   // + j*8 per issue
  int qs = q ^ srow8;                // (rowbase+j*8)&7 == srow8
  size_t A_off[4];
  int B_off[4];
#pragma unroll
  for (int j = 0; j < 4; ++j) {
    int row = rowbase + j * 8;
    A_off[j] = (size_t)(m0 + row) * 20736 + qs * 8;
    int n = n0 + row;
    int nb_ = n / 36;
    int sp = n - nb_ * 36;
    int oh = sp / 6, ow = sp - oh * 6;
    B_off[j] = ((nb_ * 20 + 2 * oh) * 20 + 2 * ow) * 256 + qs * 8;
  }
  int ldsbase = wave * 4096;  // bytes

  int fr = lane & 15, fg = lane >> 4;
  int rs = fr & 7;
  int arow[4], bcol[4];
#pragma unroll
  for (int m = 0; m < 4; ++m) {
    arow[m] = (wr * 64 + m * 16 + fr) * 128;
    bcol[m] = (wc * 64 + m * 16 + fr) * 128;
  }
  int xg0 = ((0 + fg) ^ rs) << 4;
  int xg1 = ((4 + fg) ^ rs) << 4;

  f32x4 acc[4][4] = {};

  for (int t = t_begin; t < t_end; ++t) {
    int kh = t / 9, kw = t - kh * 9;
    int toffB = (kh * 20 + kw) * 256;
    int toffA = t * 256;
    for (int kk = 0; kk < 4; ++kk) {
      int ci0 = kk * 64;
#pragma unroll
      for (int j = 0; j < 4; ++j) {
        gload_lds16(A2 + A_off[j] + toffA + ci0,
                    (char*)Al + ldsbase + j * 1024);
        gload_lds16(hT + B_off[j] + toffB + ci0,
                    (char*)Bl + ldsbase + j * 1024);
      }
      __syncthreads();  // drains vmcnt(0) -> staged data visible
#pragma unroll
      for (int s2 = 0; s2 < 2; ++s2) {
        int xg = s2 ? xg1 : xg0;
        short8 af[4], bf_[4];
#pragma unroll
        for (int m = 0; m < 4; ++m)
          af[m] = *(const short8*)((const char*)Al + arow[m] + xg);
#pragma unroll
        for (int nn = 0; nn < 4; ++nn)
          bf_[nn] = *(const short8*)((const char*)Bl + bcol[nn] + xg);
#pragma unroll
        for (int m = 0; m < 4; ++m)
#pragma unroll
          for (int nn = 0; nn < 4; ++nn)
            acc[m][nn] = __builtin_amdgcn_mfma_f32_16x16x32_bf16(
                af[m], bf_[nn], acc[m][nn], 0, 0, 0);
      }
      __syncthreads();  // all reads done before next-step staging overwrites
    }
  }
  // epilogue: atomic accumulate into u[b][co*36+s]
#pragma unroll
  for (int nn = 0; nn < 4; ++nn) {
    int cn = n0 + wc * 64 + nn * 16 + fr;
    int ob = cn / 36;
    int os = cn - ob * 36;
    float* op = u + (size_t)ob * 9216 + os;
#pragma unroll
    for (int m = 0; m < 4; ++m) {
      int row0 = m0 + wr * 64 + m * 16 + fg * 4;
#pragma unroll
      for (int qq = 0; qq < 4; ++qq)
        atomicAdd(op + (row0 + qq) * 36, acc[m][nn][qq]);
    }
  }
}

// ---------------- squash u -> ub (b-major) + ubT (ri-major), bf16 ----------------
__global__ __launch_bounds__(256) void squash_kernel(
    const float* __restrict__ u, u16* __restrict__ ub, u16* __restrict__ ubT) {
  int idx = blockIdx.x * 256 + threadIdx.x;  // 589,824 = b*1152 + r
  int b = idx / 1152, r = idx - b * 1152;
  float4 a = *(const float4*)(u + (size_t)idx * 8);
  float4 c = *(const float4*)(u + (size_t)idx * 8 + 4);
  float sq = a.x * a.x + a.y * a.y + a.z * a.z + a.w * a.w +
             c.x * c.x + c.y * c.y + c.z * c.z + c.w * c.w;
  float f = sqrtf(sq) / (1.0f + sq);
  u16 o[8];
  o[0] = f2bf(a.x * f); o[1] = f2bf(a.y * f);
  o[2] = f2bf(a.z * f); o[3] = f2bf(a.w * f);
  o[4] = f2bf(c.x * f); o[5] = f2bf(c.y * f);
  o[6] = f2bf(c.z * f); o[7] = f2bf(c.w * f);
  *(uint4*)(ub + (size_t)idx * 8) = *(uint4*)o;
#pragma unroll
  for (int i = 0; i < 8; ++i) ubT[(size_t)(r * 8 + i) * 512 + b] = o[i];
}

// ---------------- softmax over routes: cT[c][r] = softmax_r(bij[r][c]) ----------------
__global__ __launch_bounds__(256) void softmax_c_kernel(
    const float* __restrict__ bij, float* __restrict__ cT) {
  int c = blockIdx.x;
  int tid = threadIdx.x;
  __shared__ float red[256];
  float mx = -1e30f;
  for (int r = tid; r < 1152; r += 256) mx = fmaxf(mx, bij[r * 10 + c]);
  red[tid] = mx;
  __syncthreads();
  for (int s = 128; s > 0; s >>= 1) {
    if (tid < s) red[tid] = fmaxf(red[tid], red[tid + s]);
    __syncthreads();
  }
  mx = red[0];
  __syncthreads();
  float sum = 0.f;
  for (int r = tid; r < 1152; r += 256) sum += expf(bij[r * 10 + c] - mx);
  red[tid] = sum;
  __syncthreads();
  for (int s = 128; s > 0; s >>= 1) {
    if (tid < s) red[tid] += red[tid + s];
    __syncthreads();
  }
  float inv = 1.0f / red[0];
  for (int r = tid; r < 1152; r += 256)
    cT[c * 1152 + r] = expf(bij[r * 10 + c] - mx) * inv;
}

// ---------------- Wcb[co][ri] = bf16( c[r,c] * W[r,c,o,i] ) ----------------
__global__ __launch_bounds__(256) void build_wc_kernel(
    const float* __restrict__ W, const float* __restrict__ cT,
    u16* __restrict__ Wcb) {
  int idx = blockIdx.x * 256 + threadIdx.x;  // 1,474,560 = co*9216 + ri
  int co = idx / 9216, ri = idx - co * 9216;
  int c = co >> 4, o = co & 15, r = ri >> 3, i = ri & 7;
  Wcb[idx] = f2bf(cT[c * 1152 + r] * W[(size_t)r * 1280 + c * 128 + o * 8 + i]);
}

// ---------------- gemm_s: s[160co][512b] += Wcb @ ub^T (K=9216) ----------------
// grid 72 = 8 nb * 9 kz, BK=64, padded LDS rows (144B -> 2-way free).
__global__ __launch_bounds__(256) void gemm_s_kernel(
    const u16* __restrict__ Wcb, const u16* __restrict__ ub,
    float* __restrict__ s) {
  __shared__ __align__(16) u16 Asl[160 * 72];
  __shared__ __align__(16) u16 Bsl[64 * 72];
  int nb = blockIdx.x & 7, kz = blockIdx.x >> 3;
  int n0 = nb * 64, k0 = kz * 1024;
  int tid = threadIdx.x;
  int lane = tid & 63, wave = tid >> 6;
  int fr = lane & 15, fg = lane >> 4;
  f32x4 acc[10] = {};
  for (int ks = 0; ks < 16; ++ks) {
    int kb = k0 + ks * 64;
    __syncthreads();
#pragma unroll
    for (int rr = 0; rr < 5; ++rr) {
      int c = tid + rr * 256;
      int row = c >> 3, qq = c & 7;
      *(uint4*)((char*)Asl + row * 144 + qq * 16) =
          *(const uint4*)(Wcb + (size_t)row * 9216 + kb + qq * 8);
    }
#pragma unroll
    for (int rr = 0; rr < 2; ++rr) {
      int c = tid + rr * 256;
      int row = c >> 3, qq = c & 7;
      *(uint4*)((char*)Bsl + row * 144 + qq * 16) =
          *(const uint4*)(ub + (size_t)(n0 + row) * 9216 + kb + qq * 8);
    }
    __syncthreads();
#pragma unroll
    for (int s2 = 0; s2 < 2; ++s2) {
      int xg = (s2 * 4 + fg) * 16;
      short8 bf0 = *(const short8*)((char*)Bsl + (wave * 16 + fr) * 144 + xg);
#pragma unroll
      for (int m = 0; m < 10; ++m) {
        short8 af = *(const short8*)((char*)Asl + (m * 16 + fr) * 144 + xg);
        acc[m] = __builtin_amdgcn_mfma_f32_16x16x32_bf16(af, bf0, acc[m], 0, 0, 0);
      }
    }
  }
  int bcol = n0 + wave * 16 + fr;
#pragma unroll
  for (int m = 0; m < 10; ++m)
#pragma unroll
    for (int qq = 0; qq < 4; ++qq)
      atomicAdd(s + (m * 16 + fg * 4 + qq) * 512 + bcol, acc[m][qq]);
}

// ---------------- squash_v: v = squash(s); writes vb bf16 or final out ----------------
__global__ __launch_bounds__(256) void squash_v_kernel(
    const float* __restrict__ s, u16* __restrict__ vb,
    float* __restrict__ outp, int write_out) {
  int idx = blockIdx.x * 256 + threadIdx.x;  // 5120 = c*512 + b
  int c = idx >> 9, b = idx & 511;
  float vals[16];
  float sq = 0.f;
#pragma unroll
  for (int o = 0; o < 16; ++o) {
    float v = s[(c * 16 + o) * 512 + b];
    vals[o] = v;
    sq += v * v;
  }
  float f = sqrtf(sq) / (1.0f + sq);
  if (write_out) {
#pragma unroll
    for (int o = 0; o < 16; ++o) outp[((size_t)b * 10 + c) * 16 + o] = vals[o] * f;
  } else {
#pragma unroll
    for (int o = 0; o < 16; ++o) vb[(c * 16 + o) * 512 + b] = f2bf(vals[o] * f);
  }
}

// ---------------- gemm_g: G[160co][9216ri] = vb @ ubT^T (K=512b) ----------------
// grid 72 nb of 128. No split-K; direct store.
__global__ __launch_bounds__(256) void gemm_g_kernel(
    const u16* __restrict__ vb, const u16* __restrict__ ubT,
    float* __restrict__ G) {
  __shared__ __align__(16) u16 Agl[160 * 72];
  __shared__ __align__(16) u16 Bgl[128 * 72];
  int n0 = blockIdx.x * 128;
  int tid = threadIdx.x;
  int lane = tid & 63, wave = tid >> 6;
  int fr = lane & 15, fg = lane >> 4;
  f32x4 acc[10][2] = {};
  for (int ks = 0; ks < 8; ++ks) {
    int kb = ks * 64;
    __syncthreads();
#pragma unroll
    for (int rr = 0; rr < 5; ++rr) {
      int c = tid + rr * 256;
      int row = c >> 3, qq = c & 7;
      *(uint4*)((char*)Agl + row * 144 + qq * 16) =
          *(const uint4*)(vb + (size_t)row * 512 + kb + qq * 8);
    }
#pragma unroll
    for (int rr = 0; rr < 4; ++rr) {
      int c = tid + rr * 256;
      int row = c >> 3, qq = c & 7;
      *(uint4*)((char*)Bgl + row * 144 + qq * 16) =
          *(const uint4*)(ubT + (size_t)(n0 + row) * 512 + kb + qq * 8);
    }
    __syncthreads();
#pragma unroll
    for (int s2 = 0; s2 < 2; ++s2) {
      int xg = (s2 * 4 + fg) * 16;
      short8 bf_[2];
#pragma unroll
      for (int nn = 0; nn < 2; ++nn)
        bf_[nn] = *(const short8*)((char*)Bgl + (wave * 32 + nn * 16 + fr) * 144 + xg);
#pragma unroll
      for (int m = 0; m < 10; ++m) {
        short8 af = *(const short8*)((char*)Agl + (m * 16 + fr) * 144 + xg);
#pragma unroll
        for (int nn = 0; nn < 2; ++nn)
          acc[m][nn] = __builtin_amdgcn_mfma_f32_16x16x32_bf16(af, bf_[nn],
                                                              acc[m][nn], 0, 0, 0);
      }
    }
  }
#pragma unroll
  for (int m = 0; m < 10; ++m)
#pragma unroll
    for (int nn = 0; nn < 2; ++nn) {
      int ri = n0 + wave * 32 + nn * 16 + fr;
#pragma unroll
      for (int qq = 0; qq < 4; ++qq)
        G[(size_t)(m * 16 + fg * 4 + qq) * 9216 + ri] = acc[m][nn][qq];
    }
}

// ---------------- bij[r][c] += (1/512) * sum_{o,i} W[r,c,o,i] * G[c*16+o][r*8+i] ----------------
__global__ __launch_bounds__(256) void contract_kernel(
    const float* __restrict__ W, const float* __restrict__ G,
    float* __restrict__ bij) {
  int idx = blockIdx.x * 256 + threadIdx.x;  // 11520 = r*10 + c
  if (idx >= 11520) return;
  int r = idx / 10, c = idx - r * 10;
  const float* wp = W + (size_t)r * 1280 + c * 128;
  float acc = 0.f;
#pragma unroll 4
  for (int o = 0; o < 16; ++o) {
    const float* gp = G + (size_t)(c * 16 + o) * 9216 + r * 8;
#pragma unroll
    for (int i = 0; i < 8; ++i) acc = fmaf(wp[o * 8 + i], gp[i], acc);
  }
  bij[idx] += acc * (1.0f / 512.0f);
}

extern "C" void kernel_launch(void* const* d_in, const int* in_sizes, int n_in,
                              void* d_out, int out_size, void* d_ws, size_t ws_size,
                              hipStream_t stream) {
  const float* x  = (const float*)d_in[0];
  const float* w1 = (const float*)d_in[1];
  const float* b1 = (const float*)d_in[2];
  const float* w2 = (const float*)d_in[3];
  const float* b2 = (const float*)d_in[4];
  const float* W  = (const float*)d_in[5];
  char* ws = (char*)d_ws;
  u16*   hT  = (u16*)ws;
  u16*   A2  = (u16*)(ws + 104857600);
  float* u   = (float*)(ws + 115474432);
  float* bij = (float*)(ws + 134348800);
  float* cT  = (float*)(ws + 134394880);
  float* s   = (float*)(ws + 134440960);
  u16*   ub  = (u16*)ws;                 // aliases dead hT
  u16*   ubT = (u16*)(ws + 9437184);
  u16*   Wcb = (u16*)(ws + 18874368);
  u16*   vb  = (u16*)(ws + 21823488);
  float* G   = (float*)(ws + 21987328);
  float* out = (float*)d_out;

  hipMemsetAsync(bij, 0, 46080, stream);
  init_u_kernel<<<4608, 256, 0, stream>>>(b2, u);
  conv1_kernel<<<dim3(512, 2), 256, 0, stream>>>(x, w1, b1, hT);
  prep_w2_kernel<<<20736, 256, 0, stream>>>(w2, A2);
  conv2_kernel<<<1152, 256, 0, stream>>>(hT, A2, u);
  squash_kernel<<<2304, 256, 0, stream>>>(u, ub, ubT);
  for (int it = 0; it < 3; ++it) {
    softmax_c_kernel<<<10, 256, 0, stream>>>(bij, cT);
    build_wc_kernel<<<5760, 256, 0, stream>>>(W, cT, Wcb);
    hipMemsetAsync(s, 0, 327680, stream);
    gemm_s_kernel<<<72, 256, 0, stream>>>(Wcb, ub, s);
    squash_v_kernel<<<20, 256, 0, stream>>>(s, vb, out, it == 2 ? 1 : 0);
    if (it < 2) {
      gemm_g_kernel<<<72, 256, 0, stream>>>(vb, ubT, G);
      contract_kernel<<<45, 256, 0, stream>>>(W, G, bij);
    }
  }
}

// Round 3
// 735.983 us; speedup vs baseline: 6.8135x; 1.1294x over previous
//
#include <hip/hip_runtime.h>
#include <stdint.h>

// CapsuleNet forward on MI355X — round 3.
// conv1 (fp32 VALU, reg-patch) -> hT[b][y][x][ci] bf16 (channel-last)
// conv2 = implicit GEMM bf16 MFMA, 2-phase double-buffered global_load_lds,
//         BK=64, XOR-swizzle, split-K x4, atomicAdd into bias-init u
// routing: gemm_s (c*W fused staging, split-K 72) ; gemm_gc (G in LDS + contract fused)
//
// ws layout (total 134,768,640 B):
//   hT  bf16 [512][20][20][256]   @0           104,857,600
//   A2  bf16 [256][20736]         @104,857,600  10,616,832
//   u   f32  [512][9216]          @115,474,432  18,874,368
//   bij f32  [1152][10]           @134,348,800      46,080
//   cT  f32  [10][1152]           @134,394,880      46,080
//   s   f32  [160][512]           @134,440,960     327,680
//  aliased over dead hT after conv2:
//   ub  bf16 [512][9216]          @0             9,437,184
//   ubT bf16 [9216][512]          @9,437,184     9,437,184
//   vb  bf16 [160][512]           @21,823,488      163,840

typedef unsigned short u16;
typedef unsigned int u32;
typedef short short8 __attribute__((ext_vector_type(8)));
typedef float f32x4 __attribute__((ext_vector_type(4)));

__device__ __forceinline__ u16 f2bf(float f) {
  u32 u = __float_as_uint(f);
  return (u16)((u + 0x7FFFu + ((u >> 16) & 1u)) >> 16);
}

__device__ __forceinline__ void gload_lds16(const void* g, void* l) {
  __builtin_amdgcn_global_load_lds(
      (const __attribute__((address_space(1))) void*)g,
      (__attribute__((address_space(3))) void*)l, 16, 0, 0);
}

// ---------------- conv1 + bias + ReLU -> hT[b][y][x][co] bf16 ----------------
__global__ __launch_bounds__(256) void conv1_kernel(
    const float* __restrict__ x, const float* __restrict__ w1,
    const float* __restrict__ b1, u16* __restrict__ hT) {
  int b = blockIdx.x;
  int co0 = blockIdx.y * 128;
  int t = threadIdx.x;
  if (t >= 200) return;
  int oh = t / 10, ow0 = (t % 10) * 2;
  const float* xb = x + (size_t)b * 784;
  float patch[9][10];
#pragma unroll
  for (int kh = 0; kh < 9; ++kh)
#pragma unroll
    for (int j = 0; j < 10; ++j) patch[kh][j] = xb[(oh + kh) * 28 + ow0 + j];
  u16* hb = hT + ((size_t)b * 400 + oh * 20 + ow0) * 256 + co0;
  for (int c8 = 0; c8 < 16; ++c8) {
    u16 o0[8], o1[8];
#pragma unroll
    for (int cc = 0; cc < 8; ++cc) {
      int co = co0 + c8 * 8 + cc;
      const float* wc = w1 + co * 81;  // block-uniform -> s_load
      float a0 = 0.f, a1 = 0.f;
#pragma unroll
      for (int kh = 0; kh < 9; ++kh)
#pragma unroll
        for (int kw = 0; kw < 9; ++kw) {
          float wv = wc[kh * 9 + kw];
          a0 = fmaf(wv, patch[kh][kw], a0);
          a1 = fmaf(wv, patch[kh][kw + 1], a1);
        }
      float bias = b1[co];
      o0[cc] = f2bf(fmaxf(a0 + bias, 0.f));
      o1[cc] = f2bf(fmaxf(a1 + bias, 0.f));
    }
    *(uint4*)(hb + c8 * 8) = *(uint4*)o0;
    *(uint4*)(hb + 256 + c8 * 8) = *(uint4*)o1;
  }
}

// ---------------- conv2 weights: [co][ci][t] -> bf16 [co][t*256+ci] ----------------
__global__ __launch_bounds__(256) void prep_w2_kernel(
    const float* __restrict__ w2, u16* __restrict__ A2) {
  int idx = blockIdx.x * 256 + threadIdx.x;  // 5,308,416
  int co = idx / 20736, k = idx - co * 20736;
  int t = k >> 8, ci = k & 255;
  A2[idx] = f2bf(w2[(size_t)(co * 256 + ci) * 81 + t]);
}

// ---------------- u := bias (pre-init for conv2 atomic accumulation) ----------------
__global__ __launch_bounds__(256) void init_u_kernel(
    const float* __restrict__ b2, float* __restrict__ u) {
  int i = blockIdx.x * 256 + threadIdx.x;  // 1,179,648 float4s
  int b = i / 2304, j0 = (i - b * 2304) * 4;
  float4 v;
  v.x = b2[j0 / 36]; v.y = b2[(j0 + 1) / 36];
  v.z = b2[(j0 + 2) / 36]; v.w = b2[(j0 + 3) / 36];
  *(float4*)(u + (size_t)b * 9216 + j0) = v;
}

// ---------------- conv2 implicit GEMM, 2-phase double-buffered ----------------
// M=256(co) N=18432(b*36+s) K=81taps*256ci. Tile 128x128, BK=64, split-K x4.
// grid 1152 = 144 nb * 4 kz * 2 mb. Stage(t+1) issued BEFORE compute(t);
// one __syncthreads per BK step (drains vmcnt after ~300cyc of compute).
__global__ __launch_bounds__(256) void conv2_kernel(
    const u16* __restrict__ hT, const u16* __restrict__ A2,
    float* __restrict__ u) {
  __shared__ __align__(16) u16 Al[2][128 * 64];
  __shared__ __align__(16) u16 Bl[2][128 * 64];
  int bx = blockIdx.x;
  int mb = bx & 1, kz = (bx >> 1) & 3, nbk = bx >> 3;
  int m0 = mb * 128, n0 = nbk * 128;
  int t_begin = (81 * kz) >> 2, t_end = (81 * (kz + 1)) >> 2;
  int NS = (t_end - t_begin) * 4;
  int tid = threadIdx.x;
  int lane = tid & 63, wave = tid >> 6;
  int wr = wave >> 1, wc = wave & 1;

  // staging addresses: per wave 4 issues of 1KB for A and B each
  int srow8 = lane >> 3;  // 0..7
  int q = lane & 7;
  int rowbase = wave * 32 + srow8;
  int qs = q ^ srow8;  // source pre-swizzle: LDS[row][q] = global[row][q^(row&7)]
  size_t A_off[4];
  int B_off[4];
#pragma unroll
  for (int j = 0; j < 4; ++j) {
    int row = rowbase + j * 8;
    A_off[j] = (size_t)(m0 + row) * 20736 + qs * 8;
    int n = n0 + row;
    int nb_ = n / 36;
    int sp = n - nb_ * 36;
    int oh = sp / 6, ow = sp - oh * 6;
    B_off[j] = ((nb_ * 20 + 2 * oh) * 20 + 2 * ow) * 256 + qs * 8;
  }
  int ldsbase = wave * 4096;  // bytes

  int fr = lane & 15, fg = lane >> 4;
  int rs = fr & 7;
  int arow[4], bcol[4];
#pragma unroll
  for (int m = 0; m < 4; ++m) {
    arow[m] = (wr * 64 + m * 16 + fr) * 128;
    bcol[m] = (wc * 64 + m * 16 + fr) * 128;
  }
  int xg0 = ((0 + fg) ^ rs) << 4;
  int xg1 = ((4 + fg) ^ rs) << 4;

  f32x4 acc[4][4] = {};

  auto STAGE = [&](int s, int buf) {
    int t = t_begin + (s >> 2);
    int kk = s & 3;
    int kh = t / 9, kw = t - kh * 9;
    int toffA = t * 256 + kk * 64;
    int toffB = (kh * 20 + kw) * 256 + kk * 64;
#pragma unroll
    for (int j = 0; j < 4; ++j) {
      gload_lds16(A2 + A_off[j] + toffA, (char*)Al[buf] + ldsbase + j * 1024);
      gload_lds16(hT + B_off[j] + toffB, (char*)Bl[buf] + ldsbase + j * 1024);
    }
  };

  STAGE(0, 0);
  __syncthreads();
  int cur = 0;
  for (int s = 0; s < NS; ++s) {
    if (s + 1 < NS) STAGE(s + 1, cur ^ 1);  // prefetch ahead of compute
    const char* Ab = (const char*)Al[cur];
    const char* Bb = (const char*)Bl[cur];
    short8 af[4], bf_[4];
#pragma unroll
    for (int m = 0; m < 4; ++m) af[m] = *(const short8*)(Ab + arow[m] + xg0);
#pragma unroll
    for (int nn = 0; nn < 4; ++nn) bf_[nn] = *(const short8*)(Bb + bcol[nn] + xg0);
#pragma unroll
    for (int m = 0; m < 4; ++m)
#pragma unroll
      for (int nn = 0; nn < 4; ++nn)
        acc[m][nn] = __builtin_amdgcn_mfma_f32_16x16x32_bf16(
            af[m], bf_[nn], acc[m][nn], 0, 0, 0);
#pragma unroll
    for (int m = 0; m < 4; ++m) af[m] = *(const short8*)(Ab + arow[m] + xg1);
#pragma unroll
    for (int nn = 0; nn < 4; ++nn) bf_[nn] = *(const short8*)(Bb + bcol[nn] + xg1);
#pragma unroll
    for (int m = 0; m < 4; ++m)
#pragma unroll
      for (int nn = 0; nn < 4; ++nn)
        acc[m][nn] = __builtin_amdgcn_mfma_f32_16x16x32_bf16(
            af[m], bf_[nn], acc[m][nn], 0, 0, 0);
    __syncthreads();  // readers done + prefetch drained (vmcnt 0)
    cur ^= 1;
  }
  // epilogue: atomic accumulate into u[b][co*36+s] (16-lane coalesced lines)
#pragma unroll
  for (int nn = 0; nn < 4; ++nn) {
    int cn = n0 + wc * 64 + nn * 16 + fr;
    int ob = cn / 36;
    int os = cn - ob * 36;
    float* op = u + (size_t)ob * 9216 + os;
#pragma unroll
    for (int m = 0; m < 4; ++m) {
      int row0 = m0 + wr * 64 + m * 16 + fg * 4;
#pragma unroll
      for (int qq = 0; qq < 4; ++qq)
        atomicAdd(op + (row0 + qq) * 36, acc[m][nn][qq]);
    }
  }
}

// ---------------- squash u -> ub (b-major) + ubT (ri-major), bf16 ----------------
// r-major thread map: lanes span b -> ubT stores 128B-coalesced.
__global__ __launch_bounds__(256) void squash_kernel(
    const float* __restrict__ u, u16* __restrict__ ub, u16* __restrict__ ubT) {
  int idx = blockIdx.x * 256 + threadIdx.x;  // 589,824 = r*512 + b
  int r = idx >> 9, b = idx & 511;
  const float* up = u + (size_t)b * 9216 + r * 8;
  float4 a = *(const float4*)up;
  float4 c = *(const float4*)(up + 4);
  float sq = a.x * a.x + a.y * a.y + a.z * a.z + a.w * a.w +
             c.x * c.x + c.y * c.y + c.z * c.z + c.w * c.w;
  float f = sqrtf(sq) / (1.0f + sq);
  u16 o[8];
  o[0] = f2bf(a.x * f); o[1] = f2bf(a.y * f);
  o[2] = f2bf(a.z * f); o[3] = f2bf(a.w * f);
  o[4] = f2bf(c.x * f); o[5] = f2bf(c.y * f);
  o[6] = f2bf(c.z * f); o[7] = f2bf(c.w * f);
  *(uint4*)(ub + ((size_t)b * 1152 + r) * 8) = *(uint4*)o;
#pragma unroll
  for (int i = 0; i < 8; ++i) ubT[(size_t)(r * 8 + i) * 512 + b] = o[i];
}

// ---------------- softmax over routes: cT[c][r] = softmax_r(bij[r][c]) ----------------
__global__ __launch_bounds__(256) void softmax_c_kernel(
    const float* __restrict__ bij, float* __restrict__ cT) {
  int c = blockIdx.x;
  int tid = threadIdx.x;
  __shared__ float red[256];
  float mx = -1e30f;
  for (int r = tid; r < 1152; r += 256) mx = fmaxf(mx, bij[r * 10 + c]);
  red[tid] = mx;
  __syncthreads();
  for (int s = 128; s > 0; s >>= 1) {
    if (tid < s) red[tid] = fmaxf(red[tid], red[tid + s]);
    __syncthreads();
  }
  mx = red[0];
  __syncthreads();
  float sum = 0.f;
  for (int r = tid; r < 1152; r += 256) sum += expf(bij[r * 10 + c] - mx);
  red[tid] = sum;
  __syncthreads();
  for (int s = 128; s > 0; s >>= 1) {
    if (tid < s) red[tid] += red[tid + s];
    __syncthreads();
  }
  float inv = 1.0f / red[0];
  for (int r = tid; r < 1152; r += 256)
    cT[c * 1152 + r] = expf(bij[r * 10 + c] - mx) * inv;
}

// ---------------- gemm_s: s[160co][512b] += (c*W) @ ub^T, K=9216 ----------------
// split-K 72 (K=128/block, 2 BK steps), grid 576 = 8 nb * 72 kz.
// A tile built on the fly from W f32 * cT (fuses build_wc). Pitch 144B (0-conflict).
__global__ __launch_bounds__(256) void gemm_s_kernel(
    const float* __restrict__ W, const float* __restrict__ cT,
    const u16* __restrict__ ub, float* __restrict__ s) {
  __shared__ __align__(16) u16 Asl[160 * 72];
  __shared__ __align__(16) u16 Bsl[64 * 72];
  int nb = blockIdx.x & 7, kzi = blockIdx.x >> 3;
  int n0 = nb * 64, k0 = kzi * 128;
  int tid = threadIdx.x;
  int lane = tid & 63, wave = tid >> 6;
  int fr = lane & 15, fg = lane >> 4;
  f32x4 acc[10] = {};
#pragma unroll
  for (int st = 0; st < 2; ++st) {
    int kb = k0 + st * 64;
    __syncthreads();
#pragma unroll
    for (int j = 0; j < 5; ++j) {  // A: 160 rows x 8 chunks
      int c5 = tid + j * 256;
      int row = c5 >> 3, qq = c5 & 7;
      int cls = row >> 4, o = row & 15;
      int r = (kb + qq * 8) >> 3;  // 8 consecutive k = one r
      const float* wp = W + (size_t)r * 1280 + cls * 128 + o * 8;
      float4 w0 = *(const float4*)wp;
      float4 w1 = *(const float4*)(wp + 4);
      float cs = cT[cls * 1152 + r];
      u16 ov[8];
      ov[0] = f2bf(w0.x * cs); ov[1] = f2bf(w0.y * cs);
      ov[2] = f2bf(w0.z * cs); ov[3] = f2bf(w0.w * cs);
      ov[4] = f2bf(w1.x * cs); ov[5] = f2bf(w1.y * cs);
      ov[6] = f2bf(w1.z * cs); ov[7] = f2bf(w1.w * cs);
      *(uint4*)((char*)Asl + row * 144 + qq * 16) = *(uint4*)ov;
    }
#pragma unroll
    for (int j = 0; j < 2; ++j) {  // B: 64 rows x 8 chunks
      int c2 = tid + j * 256;
      int row = c2 >> 3, qq = c2 & 7;
      *(uint4*)((char*)Bsl + row * 144 + qq * 16) =
          *(const uint4*)(ub + (size_t)(n0 + row) * 9216 + kb + qq * 8);
    }
    __syncthreads();
#pragma unroll
    for (int s2 = 0; s2 < 2; ++s2) {
      int xg = (s2 * 4 + fg) * 16;
      short8 bf0 = *(const short8*)((char*)Bsl + (wave * 16 + fr) * 144 + xg);
#pragma unroll
      for (int m = 0; m < 10; ++m) {
        short8 af = *(const short8*)((char*)Asl + (m * 16 + fr) * 144 + xg);
        acc[m] = __builtin_amdgcn_mfma_f32_16x16x32_bf16(af, bf0, acc[m], 0, 0, 0);
      }
    }
  }
  int bcol = n0 + wave * 16 + fr;
#pragma unroll
  for (int m = 0; m < 10; ++m)
#pragma unroll
    for (int qq = 0; qq < 4; ++qq)
      atomicAdd(s + (m * 16 + fg * 4 + qq) * 512 + bcol, acc[m][qq]);
}

// ---------------- squash_v: v = squash(s); re-zeros s for next iteration ----------------
__global__ __launch_bounds__(256) void squash_v_kernel(
    float* __restrict__ s, u16* __restrict__ vb,
    float* __restrict__ outp, int write_out) {
  int idx = blockIdx.x * 256 + threadIdx.x;  // 5120 = c*512 + b
  int c = idx >> 9, b = idx & 511;
  float vals[16];
  float sq = 0.f;
#pragma unroll
  for (int o = 0; o < 16; ++o) {
    float v = s[(c * 16 + o) * 512 + b];
    vals[o] = v;
    sq += v * v;
  }
#pragma unroll
  for (int o = 0; o < 16; ++o) s[(c * 16 + o) * 512 + b] = 0.f;
  float f = sqrtf(sq) / (1.0f + sq);
  if (write_out) {
#pragma unroll
    for (int o = 0; o < 16; ++o) outp[((size_t)b * 10 + c) * 16 + o] = vals[o] * f;
  } else {
#pragma unroll
    for (int o = 0; o < 16; ++o) vb[(c * 16 + o) * 512 + b] = f2bf(vals[o] * f);
  }
}

// ---------------- gemm_gc: G = vb @ ubT^T (in LDS) then bij += W.G/512 ----------------
// grid 144 = 72 nb (128 ri) * 2 kz (256 b each). Contract is linear in G ->
// split-K partials add via atomicAdd on bij. G_lds pitch 129 f32.
__global__ __launch_bounds__(256) void gemm_gc_kernel(
    const u16* __restrict__ vb, const u16* __restrict__ ubT,
    const float* __restrict__ W, float* __restrict__ bij) {
  __shared__ __align__(16) u16 Agl[160 * 72];
  __shared__ __align__(16) u16 Bgl[128 * 72];
  __shared__ float Gl[160 * 129];
  int nb = blockIdx.x % 72, kzi = blockIdx.x / 72;
  int n0 = nb * 128, k0 = kzi * 256;
  int tid = threadIdx.x;
  int lane = tid & 63, wave = tid >> 6;
  int fr = lane & 15, fg = lane >> 4;
  f32x4 acc[10][2] = {};
  for (int st = 0; st < 4; ++st) {
    int kb = k0 + st * 64;
    __syncthreads();
#pragma unroll
    for (int j = 0; j < 5; ++j) {
      int c5 = tid + j * 256;
      int row = c5 >> 3, qq = c5 & 7;
      *(uint4*)((char*)Agl + row * 144 + qq * 16) =
          *(const uint4*)(vb + (size_t)row * 512 + kb + qq * 8);
    }
#pragma unroll
    for (int j = 0; j < 4; ++j) {
      int c4 = tid + j * 256;
      int row = c4 >> 3, qq = c4 & 7;
      *(uint4*)((char*)Bgl + row * 144 + qq * 16) =
          *(const uint4*)(ubT + (size_t)(n0 + row) * 512 + kb + qq * 8);
    }
    __syncthreads();
#pragma unroll
    for (int s2 = 0; s2 < 2; ++s2) {
      int xg = (s2 * 4 + fg) * 16;
      short8 bfv[2];
#pragma unroll
      for (int nn = 0; nn < 2; ++nn)
        bfv[nn] = *(const short8*)((char*)Bgl + (wave * 32 + nn * 16 + fr) * 144 + xg);
#pragma unroll
      for (int m = 0; m < 10; ++m) {
        short8 af = *(const short8*)((char*)Agl + (m * 16 + fr) * 144 + xg);
#pragma unroll
        for (int nn = 0; nn < 2; ++nn)
          acc[m][nn] = __builtin_amdgcn_mfma_f32_16x16x32_bf16(af, bfv[nn],
                                                              acc[m][nn], 0, 0, 0);
      }
    }
  }
  // G -> LDS
#pragma unroll
  for (int m = 0; m < 10; ++m)
#pragma unroll
    for (int nn = 0; nn < 2; ++nn) {
      int col = wave * 32 + nn * 16 + fr;
#pragma unroll
      for (int qq = 0; qq < 4; ++qq)
        Gl[(m * 16 + fg * 4 + qq) * 129 + col] = acc[m][nn][qq];
    }
  __syncthreads();
  // contract: bij[r][c] += (1/512) sum_{o,i} W[r,c,o,i] * G[c*16+o][rl*8+i]
  if (tid < 160) {
    int rl = tid / 10, c = tid - rl * 10;
    int r = (n0 >> 3) + rl;
    const float* wp = W + (size_t)r * 1280 + c * 128;
    float a = 0.f;
#pragma unroll 4
    for (int o = 0; o < 16; ++o) {
      const float* gp = &Gl[(c * 16 + o) * 129 + rl * 8];
#pragma unroll
      for (int i = 0; i < 8; ++i) a = fmaf(wp[o * 8 + i], gp[i], a);
    }
    atomicAdd(&bij[r * 10 + c], a * (1.0f / 512.0f));
  }
}

extern "C" void kernel_launch(void* const* d_in, const int* in_sizes, int n_in,
                              void* d_out, int out_size, void* d_ws, size_t ws_size,
                              hipStream_t stream) {
  const float* x  = (const float*)d_in[0];
  const float* w1 = (const float*)d_in[1];
  const float* b1 = (const float*)d_in[2];
  const float* w2 = (const float*)d_in[3];
  const float* b2 = (const float*)d_in[4];
  const float* W  = (const float*)d_in[5];
  char* ws = (char*)d_ws;
  u16*   hT  = (u16*)ws;
  u16*   A2  = (u16*)(ws + 104857600);
  float* u   = (float*)(ws + 115474432);
  float* bij = (float*)(ws + 134348800);
  float* cT  = (float*)(ws + 134394880);
  float* s   = (float*)(ws + 134440960);
  u16*   ub  = (u16*)ws;                 // aliases dead hT
  u16*   ubT = (u16*)(ws + 9437184);
  u16*   vb  = (u16*)(ws + 21823488);
  float* out = (float*)d_out;

  hipMemsetAsync(bij, 0, 46080, stream);
  hipMemsetAsync(s, 0, 327680, stream);
  init_u_kernel<<<4608, 256, 0, stream>>>(b2, u);
  conv1_kernel<<<dim3(512, 2), 256, 0, stream>>>(x, w1, b1, hT);
  prep_w2_kernel<<<20736, 256, 0, stream>>>(w2, A2);
  conv2_kernel<<<1152, 256, 0, stream>>>(hT, A2, u);
  squash_kernel<<<2304, 256, 0, stream>>>(u, ub, ubT);
  for (int it = 0; it < 3; ++it) {
    softmax_c_kernel<<<10, 256, 0, stream>>>(bij, cT);
    gemm_s_kernel<<<576, 256, 0, stream>>>(W, cT, ub, s);
    squash_v_kernel<<<20, 256, 0, stream>>>(s, vb, out, it == 2 ? 1 : 0);
    if (it < 2) gemm_gc_kernel<<<144, 256, 0, stream>>>(vb, ubT, W, bij);
  }
}